// Round 1
// baseline (1675.995 us; speedup 1.0000x reference)
//
#include <hip/hip_runtime.h>

// CKAFormer: 6 iterations of { row-L2-norm -> MLP+softmax -> X = Xn + g*P@PtX - g*Xn@G }
// then final MLP. All big GEMMs are bf16 MFMA (16x16x32) in "NT" form (both operands
// row-major, K innermost) via a materialized XnT; f32 master X lives in d_in[0] (harness
// restores inputs before every launch). Workspace use: ~75.5 MB.

#define N_ROWS 16384
#define DIM 1024
#define HID 16
#define OUTD 64
#define DEPTH 6
#define GAMMA 1e-4f

typedef short bf16x8 __attribute__((ext_vector_type(8)));
typedef unsigned short u16x8 __attribute__((ext_vector_type(8)));
typedef float f32x4 __attribute__((ext_vector_type(4)));

__device__ __forceinline__ unsigned short f2bf(float f) {
    unsigned u = __builtin_bit_cast(unsigned, f);
    u += 0x7fffu + ((u >> 16) & 1u);   // round-to-nearest-even
    return (unsigned short)(u >> 16);
}

// ---------------------------------------------------------------------------
// Row L2 norm: rinv[row] = 1/||X[row]||; Xb = bf16(X*rinv). apply=0 -> plain cast.
__global__ __launch_bounds__(256) void rownorm_k(const float* __restrict__ X,
        float* __restrict__ rinv, ushort* __restrict__ Xb, int apply) {
    int row = blockIdx.x, t = threadIdx.x;
    float4 v = ((const float4*)(X + (size_t)row * DIM))[t];
    float ss = v.x * v.x + v.y * v.y + v.z * v.z + v.w * v.w;
    for (int o = 32; o > 0; o >>= 1) ss += __shfl_down(ss, o);
    __shared__ float ws[4];
    if ((t & 63) == 0) ws[t >> 6] = ss;
    __syncthreads();
    float total = ws[0] + ws[1] + ws[2] + ws[3];
    float ri = 1.0f;
    if (apply) ri = 1.0f / sqrtf(total);
    if (apply && t == 0) rinv[row] = ri;
    ushort4 o4;
    o4.x = f2bf(v.x * ri); o4.y = f2bf(v.y * ri);
    o4.z = f2bf(v.z * ri); o4.w = f2bf(v.w * ri);
    ((ushort4*)(Xb + (size_t)row * DIM))[t] = o4;
}

// ---------------------------------------------------------------------------
// XnT[d][k] = bf16(X[k][d] * rinv[k]).  64x64 f32 LDS tile, stride 65 (conflict-free).
__global__ __launch_bounds__(256) void transpose_k(const float* __restrict__ X,
        const float* __restrict__ rinv, ushort* __restrict__ XnT) {
    int r0 = blockIdx.x * 64;   // source row (k) tile in [0, 16384)
    int c0 = blockIdx.y * 64;   // source col (d) tile in [0, 1024)
    int t = threadIdx.x;
    __shared__ float ts[64 * 65];
    __shared__ float riS[64];
    if (t < 64) riS[t] = rinv[r0 + t];
    __syncthreads();
#pragma unroll
    for (int i = 0; i < 4; ++i) {
        int idx = i * 256 + t;
        int r = idx >> 4;              // 0..63
        int c4 = (idx & 15) << 2;      // 0..60
        float4 v = *(const float4*)(X + (size_t)(r0 + r) * DIM + c0 + c4);
        float s = riS[r];
        float* p = &ts[r * 65 + c4];
        p[0] = v.x * s; p[1] = v.y * s; p[2] = v.z * s; p[3] = v.w * s;
    }
    __syncthreads();
#pragma unroll
    for (int i = 0; i < 2; ++i) {
        int g = i * 256 + t;
        int c = g >> 3;                // 0..63 (output row = dim index)
        int rg = g & 7;                // 8-elem group along k
        u16x8 pk;
#pragma unroll
        for (int u = 0; u < 8; ++u) pk[u] = f2bf(ts[(rg * 8 + u) * 65 + c]);
        *(u16x8*)(XnT + (size_t)(c0 + c) * N_ROWS + r0 + rg * 8) = pk;
    }
}

// ---------------------------------------------------------------------------
// W1T[h][j] = bf16(W1[j][h])  (16 x 1024), once per launch.
__global__ __launch_bounds__(256) void prep_w1t_k(const float* __restrict__ W1,
        ushort* __restrict__ W1T) {
    int idx = blockIdx.x * 256 + threadIdx.x;   // 16384 total
    int h = idx >> 10, j = idx & 1023;
    W1T[idx] = f2bf(W1[j * HID + h]);
}

// ---------------------------------------------------------------------------
// z[m][h] = sum_k Xb[m][k]*W1T[h][k] + b1[h].  Direct-from-global MFMA (no reuse to tile).
__global__ __launch_bounds__(256) void zgemm_k(const ushort* __restrict__ Xb,
        const ushort* __restrict__ W1T, const float* __restrict__ b1,
        float* __restrict__ z) {
    int t = threadIdx.x;
    int wave = t >> 6, lane = t & 63;
    int rl = lane & 15, q = lane >> 4;
    int rowbase = blockIdx.x * 64 + wave * 16;
    const ushort* arow = Xb + (size_t)(rowbase + rl) * DIM + q * 8;
    const ushort* brow = W1T + (size_t)rl * DIM + q * 8;
    f32x4 acc = {0.f, 0.f, 0.f, 0.f};
#pragma unroll 8
    for (int kt = 0; kt < DIM; kt += 32) {
        bf16x8 a = *(const bf16x8*)(arow + kt);
        bf16x8 b = *(const bf16x8*)(brow + kt);
        acc = __builtin_amdgcn_mfma_f32_16x16x32_bf16(a, b, acc, 0, 0, 0);
    }
#pragma unroll
    for (int rg = 0; rg < 4; ++rg) {
        int m = rowbase + q * 4 + rg;
        z[(size_t)m * HID + rl] = acc[rg] + b1[rl];
    }
}

// ---------------------------------------------------------------------------
// Per row: h = relu(z); logits = h@W2 + b2; softmax -> P (bf16) + PT (bf16),
// or (do_softmax=0) write logits f32 to out (final head).
__global__ __launch_bounds__(256) void head_k(const float* __restrict__ z,
        const float* __restrict__ W2, const float* __restrict__ b2,
        ushort* __restrict__ P, ushort* __restrict__ PT,
        float* __restrict__ out, int do_softmax) {
    __shared__ float w2s[HID * OUTD];
    __shared__ float b2s[OUTD];
    int t = threadIdx.x;
    ((float4*)w2s)[t] = ((const float4*)W2)[t];   // 1024 floats
    if (t < OUTD) b2s[t] = b2[t];
    __syncthreads();
    int m = blockIdx.x * 256 + t;
    float h[HID];
    const float4* zp = (const float4*)(z + (size_t)m * HID);
#pragma unroll
    for (int i = 0; i < 4; ++i) {
        float4 v = zp[i];
        h[i * 4 + 0] = fmaxf(v.x, 0.f); h[i * 4 + 1] = fmaxf(v.y, 0.f);
        h[i * 4 + 2] = fmaxf(v.z, 0.f); h[i * 4 + 3] = fmaxf(v.w, 0.f);
    }
    float lo[OUTD];
#pragma unroll
    for (int o = 0; o < OUTD; ++o) lo[o] = b2s[o];
    for (int i = 0; i < HID; ++i) {
        float hv = h[i];
#pragma unroll
        for (int o = 0; o < OUTD; ++o) lo[o] += hv * w2s[i * OUTD + o];
    }
    if (do_softmax) {
        float mx = lo[0];
#pragma unroll
        for (int o = 1; o < OUTD; ++o) mx = fmaxf(mx, lo[o]);
        float sm = 0.f;
#pragma unroll
        for (int o = 0; o < OUTD; ++o) { float e = __expf(lo[o] - mx); lo[o] = e; sm += e; }
        float inv = 1.0f / sm;
#pragma unroll
        for (int o8 = 0; o8 < 8; ++o8) {
            u16x8 pk;
#pragma unroll
            for (int u = 0; u < 8; ++u) pk[u] = f2bf(lo[o8 * 8 + u] * inv);
            ((u16x8*)(P + (size_t)m * OUTD))[o8] = pk;
        }
#pragma unroll
        for (int o = 0; o < OUTD; ++o) PT[(size_t)o * N_ROWS + m] = f2bf(lo[o] * inv);
    } else {
        float4* op = (float4*)(out + (size_t)m * OUTD);
#pragma unroll
        for (int o4 = 0; o4 < 16; ++o4) {
            float4 v; v.x = lo[o4 * 4 + 0]; v.y = lo[o4 * 4 + 1];
            v.z = lo[o4 * 4 + 2]; v.w = lo[o4 * 4 + 3];
            op[o4] = v;
        }
    }
}

// ---------------------------------------------------------------------------
// Cast G_f32 (negated) and PtXT_f32 (contiguous after it) to bf16 in one pass.
__global__ __launch_bounds__(256) void castgp_k(const float* __restrict__ Gf,
        ushort* __restrict__ Gb) {
    int idx = blockIdx.x * 256 + threadIdx.x;       // over (1024*1024 + 1024*64)/4
    float sc = (idx < (DIM * DIM / 4)) ? -1.0f : 1.0f;
    float4 v = ((const float4*)Gf)[idx];
    ushort4 o;
    o.x = f2bf(v.x * sc); o.y = f2bf(v.y * sc);
    o.z = f2bf(v.z * sc); o.w = f2bf(v.w * sc);
    ((ushort4*)Gb)[idx] = o;
}

// ---------------------------------------------------------------------------
// NT MFMA GEMM: C[m][n] (+)= sum_k A[m][k]*B[n][k] over up to 2 segments.
// Seg0 supports split-K via blockIdx.z (chunk = k0len). EPI 0: atomicAdd f32 C.
// EPI 1: X[m][n] = X[m][n]*rinv[m] + gamma*acc  (in-place update epilogue).
// LDS tiles are [rows][8 x 16B k-groups], XOR-swizzled: group sg holds global
// k-group sg ^ (row&7)  -> conflict-free ds_read_b128 fragments.
template<int BM, int BN, int EPI>
__global__ __launch_bounds__(256) void gemm_nt_k(
        const ushort* __restrict__ A0, int lda0,
        const ushort* __restrict__ B0, int ldb0, int k0len,
        const ushort* __restrict__ A1, int lda1,
        const ushort* __restrict__ B1, int ldb1, int k1len,
        float* __restrict__ C, int ldc,
        const float* __restrict__ rinv, float gamma) {
    constexpr int WTN = BN / 2;
    constexpr int NF = WTN / 16;
    __shared__ ushort lsA[BM * 64];
    __shared__ ushort lsB[BN * 64];
    int t = threadIdx.x;
    int wave = t >> 6, lane = t & 63;
    int rl = lane & 15, q = lane >> 4;
    int wm = wave & 1, wn = wave >> 1;
    int m0 = blockIdx.x * BM, n0 = blockIdx.y * BN;

    f32x4 acc[4][NF];
#pragma unroll
    for (int i = 0; i < 4; ++i)
#pragma unroll
        for (int j = 0; j < NF; ++j) acc[i][j] = f32x4{0.f, 0.f, 0.f, 0.f};

    for (int seg = 0; seg < 2; ++seg) {
        const ushort* A = seg ? A1 : A0;
        const ushort* B = seg ? B1 : B0;
        int lda = seg ? lda1 : lda0;
        int ldb = seg ? ldb1 : ldb0;
        int kb = seg ? 0 : (int)blockIdx.z * k0len;
        int klen = seg ? k1len : k0len;
        if (klen == 0) continue;
        for (int kt = 0; kt < klen; kt += 64) {
            // stage A tile (BM x 64) and B tile (BN x 64), swizzled
            for (int g = t; g < BM * 8; g += 256) {
                int row = g >> 3, sg = g & 7;
                int gk = sg ^ (row & 7);
                *(uint4*)&lsA[row * 64 + sg * 8] =
                    *(const uint4*)(A + (size_t)(m0 + row) * lda + kb + kt + gk * 8);
            }
            for (int g = t; g < BN * 8; g += 256) {
                int row = g >> 3, sg = g & 7;
                int gk = sg ^ (row & 7);
                *(uint4*)&lsB[row * 64 + sg * 8] =
                    *(const uint4*)(B + (size_t)(n0 + row) * ldb + kb + kt + gk * 8);
            }
            __syncthreads();
#pragma unroll
            for (int s = 0; s < 2; ++s) {
                bf16x8 af[4], bfr[NF];
#pragma unroll
                for (int i = 0; i < 4; ++i) {
                    int row = wm * 64 + i * 16 + rl;
                    int sg = ((s << 2) | q) ^ (row & 7);
                    af[i] = *(const bf16x8*)&lsA[row * 64 + sg * 8];
                }
#pragma unroll
                for (int j = 0; j < NF; ++j) {
                    int row = wn * WTN + j * 16 + rl;
                    int sg = ((s << 2) | q) ^ (row & 7);
                    bfr[j] = *(const bf16x8*)&lsB[row * 64 + sg * 8];
                }
#pragma unroll
                for (int i = 0; i < 4; ++i)
#pragma unroll
                    for (int j = 0; j < NF; ++j)
                        acc[i][j] = __builtin_amdgcn_mfma_f32_16x16x32_bf16(
                            af[i], bfr[j], acc[i][j], 0, 0, 0);
            }
            __syncthreads();
        }
    }

#pragma unroll
    for (int i = 0; i < 4; ++i)
#pragma unroll
        for (int j = 0; j < NF; ++j)
#pragma unroll
            for (int rg = 0; rg < 4; ++rg) {
                int m = m0 + wm * 64 + i * 16 + q * 4 + rg;
                int n = n0 + wn * WTN + j * 16 + rl;
                float v = acc[i][j][rg];
                if (EPI == 0) {
                    atomicAdd(&C[(size_t)m * ldc + n], v);
                } else {
                    size_t idx = (size_t)m * ldc + n;
                    C[idx] = C[idx] * rinv[m] + gamma * v;
                }
            }
}

// ---------------------------------------------------------------------------
extern "C" void kernel_launch(void* const* d_in, const int* in_sizes, int n_in,
                              void* d_out, int out_size, void* d_ws, size_t ws_size,
                              hipStream_t stream) {
    float* X = (float*)d_in[0];                 // f32 master X, updated in place
    const float* W1 = (const float*)d_in[1];
    const float* b1 = (const float*)d_in[2];
    const float* W2 = (const float*)d_in[3];
    const float* b2 = (const float*)d_in[4];
    float* out = (float*)d_out;
    char* ws = (char*)d_ws;

    constexpr size_t O_Xnb   = 0;                                     // 33,554,432 B
    constexpr size_t O_XnT   = O_Xnb + (size_t)N_ROWS * DIM * 2;      // 33,554,432
    constexpr size_t O_Pb    = O_XnT + (size_t)DIM * N_ROWS * 2;      //  2,097,152
    constexpr size_t O_PTb   = O_Pb + (size_t)N_ROWS * OUTD * 2;      //  2,097,152
    constexpr size_t O_Gf    = O_PTb + (size_t)OUTD * N_ROWS * 2;     //  4,194,304
    constexpr size_t O_PtXTf = O_Gf + (size_t)DIM * DIM * 4;          //    262,144
    constexpr size_t O_Gb    = O_PtXTf + (size_t)DIM * OUTD * 4;      //  2,097,152
    constexpr size_t O_PtXTb = O_Gb + (size_t)DIM * DIM * 2;          //    131,072
    constexpr size_t O_rinv  = O_PtXTb + (size_t)DIM * OUTD * 2;      //     65,536
    constexpr size_t O_z     = O_rinv + (size_t)N_ROWS * 4;           //  1,048,576
    constexpr size_t O_W1T   = O_z + (size_t)N_ROWS * HID * 4;        //     32,768
    // total ~79.1 MB

    ushort* Xnb   = (ushort*)(ws + O_Xnb);
    ushort* XnT   = (ushort*)(ws + O_XnT);
    ushort* Pb    = (ushort*)(ws + O_Pb);
    ushort* PTb   = (ushort*)(ws + O_PTb);
    float*  Gf    = (float*)(ws + O_Gf);       // PtXTf contiguous after Gf
    ushort* Gb    = (ushort*)(ws + O_Gb);      // PtXTb contiguous after Gb
    ushort* PtXTb = (ushort*)(ws + O_PtXTb);
    float*  riv   = (float*)(ws + O_rinv);
    float*  z     = (float*)(ws + O_z);
    ushort* W1T   = (ushort*)(ws + O_W1T);
    float*  PtXTf = (float*)(ws + O_PtXTf);
    (void)PtXTf; (void)in_sizes; (void)n_in; (void)out_size; (void)ws_size;

    prep_w1t_k<<<64, 256, 0, stream>>>(W1, W1T);

    for (int it = 0; it < DEPTH; ++it) {
        rownorm_k<<<N_ROWS, 256, 0, stream>>>(X, riv, Xnb, 1);
        transpose_k<<<dim3(N_ROWS / 64, DIM / 64), 256, 0, stream>>>(X, riv, XnT);
        zgemm_k<<<N_ROWS / 64, 256, 0, stream>>>(Xnb, W1T, b1, z);
        head_k<<<N_ROWS / 256, 256, 0, stream>>>(z, W2, b2, Pb, PTb, nullptr, 1);
        hipMemsetAsync(Gf, 0, (size_t)(DIM * DIM + DIM * OUTD) * sizeof(float), stream);
        // G = XnT . XnT^T  (split-K 8)
        gemm_nt_k<128, 128, 0><<<dim3(8, 8, 8), 256, 0, stream>>>(
            XnT, N_ROWS, XnT, N_ROWS, 2048,
            nullptr, 0, nullptr, 0, 0,
            Gf, DIM, nullptr, 0.f);
        // PtX^T = XnT . PT^T  (split-K 32)
        gemm_nt_k<128, 64, 0><<<dim3(8, 1, 32), 256, 0, stream>>>(
            XnT, N_ROWS, PTb, N_ROWS, 512,
            nullptr, 0, nullptr, 0, 0,
            (float*)(ws + O_PtXTf), OUTD, nullptr, 0.f);
        castgp_k<<<(DIM * DIM + DIM * OUTD) / 1024, 256, 0, stream>>>(Gf, Gb);
        // X = Xn + gamma*(P @ PtX) - gamma*(Xn @ G)   [G sign folded into Gb]
        gemm_nt_k<128, 128, 1><<<dim3(N_ROWS / 128, DIM / 128, 1), 256, 0, stream>>>(
            Pb, OUTD, PtXTb, OUTD, OUTD,
            Xnb, DIM, Gb, DIM, DIM,
            X, DIM, riv, GAMMA);
    }

    // final: out = relu(X@W1 + b1) @ W2 + b2  (unnormalized X)
    rownorm_k<<<N_ROWS, 256, 0, stream>>>(X, riv, Xnb, 0);
    zgemm_k<<<N_ROWS / 64, 256, 0, stream>>>(Xnb, W1T, b1, z);
    head_k<<<N_ROWS / 256, 256, 0, stream>>>(z, W2, b2, nullptr, nullptr, out, 0);
}

// Round 2
// 1498.218 us; speedup vs baseline: 1.1187x; 1.1187x over previous
//
#include <hip/hip_runtime.h>

// CKAFormer: 6 iterations of { row-L2-norm -> MLP+softmax -> X = Xn + g*P@PtX - g*Xn@G }
// then final MLP. All big GEMMs are bf16 MFMA (16x16x32) in "NT" form.
// R2: GEMM staging via __builtin_amdgcn_global_load_lds (16B). Because the DMA writes
// LDS at wave-uniform-base + lane*16 (no per-lane scatter), the XOR bank-swizzle is
// baked into the GLOBAL layout of every bf16 GEMM operand: within each 64-element
// k-tile, storage 16B-group p holds logical group p^(row&7). Producers (rownorm,
// transpose, head, castgp) write swizzled; zgemm unswizzles on read; gemm fragment
// reads are unchanged (identical LDS invariant as R1, which measured 0 bank conflicts).
// G gemm split-K 16 (1024 blocks, 4/CU), PtXT split-K 64.

#define N_ROWS 16384
#define DIM 1024
#define HID 16
#define OUTD 64
#define DEPTH 6
#define GAMMA 1e-4f

typedef short bf16x8 __attribute__((ext_vector_type(8)));
typedef unsigned short u16x8 __attribute__((ext_vector_type(8)));
typedef float f32x4 __attribute__((ext_vector_type(4)));

#define AS1C(p) ((const __attribute__((address_space(1))) void*)(p))
#define AS3(p)  ((__attribute__((address_space(3))) void*)(p))

__device__ __forceinline__ unsigned short f2bf(float f) {
    unsigned u = __builtin_bit_cast(unsigned, f);
    u += 0x7fffu + ((u >> 16) & 1u);   // round-to-nearest-even
    return (unsigned short)(u >> 16);
}

// ---------------------------------------------------------------------------
// Row L2 norm: rinv[row] = 1/||X[row]||; Xb = bf16(X*rinv), k-group swizzled.
__global__ __launch_bounds__(256) void rownorm_k(const float* __restrict__ X,
        float* __restrict__ rinv, ushort* __restrict__ Xb, int apply) {
    int row = blockIdx.x, t = threadIdx.x;
    float4 v = ((const float4*)(X + (size_t)row * DIM))[t];
    float ss = v.x * v.x + v.y * v.y + v.z * v.z + v.w * v.w;
    for (int o = 32; o > 0; o >>= 1) ss += __shfl_down(ss, o);
    __shared__ float ws[4];
    if ((t & 63) == 0) ws[t >> 6] = ss;
    __syncthreads();
    float total = ws[0] + ws[1] + ws[2] + ws[3];
    float ri = 1.0f;
    if (apply) ri = 1.0f / sqrtf(total);
    if (apply && t == 0) rinv[row] = ri;
    ushort4 o4;
    o4.x = f2bf(v.x * ri); o4.y = f2bf(v.y * ri);
    o4.z = f2bf(v.z * ri); o4.w = f2bf(v.w * ri);
    int e = t * 4;                        // logical element index
    int gl = (e >> 3) & 7;                // logical 16B group within 64-elem tile
    int idx = (e & ~63) | ((gl ^ (row & 7)) << 3) | (e & 7);
    *(ushort4*)(Xb + (size_t)row * DIM + idx) = o4;
}

// ---------------------------------------------------------------------------
// XnT[d][k] = bf16(X[k][d] * rinv[k]), k-group swizzled by (d&7).
__global__ __launch_bounds__(256) void transpose_k(const float* __restrict__ X,
        const float* __restrict__ rinv, ushort* __restrict__ XnT) {
    int r0 = blockIdx.x * 64;   // source row (k) tile in [0, 16384)
    int c0 = blockIdx.y * 64;   // source col (d) tile in [0, 1024)
    int t = threadIdx.x;
    __shared__ float ts[64 * 65];
    __shared__ float riS[64];
    if (t < 64) riS[t] = rinv[r0 + t];
    __syncthreads();
#pragma unroll
    for (int i = 0; i < 4; ++i) {
        int idx = i * 256 + t;
        int r = idx >> 4;              // 0..63
        int c4 = (idx & 15) << 2;      // 0..60
        float4 v = *(const float4*)(X + (size_t)(r0 + r) * DIM + c0 + c4);
        float s = riS[r];
        float* p = &ts[r * 65 + c4];
        p[0] = v.x * s; p[1] = v.y * s; p[2] = v.z * s; p[3] = v.w * s;
    }
    __syncthreads();
#pragma unroll
    for (int i = 0; i < 2; ++i) {
        int g = i * 256 + t;
        int c = g >> 3;                // 0..63 (output row = dim index)
        int rg = g & 7;                // logical 8-elem group along k
        u16x8 pk;
#pragma unroll
        for (int u = 0; u < 8; ++u) pk[u] = f2bf(ts[(rg * 8 + u) * 65 + c]);
        // store logical group rg at swizzled position rg^(d&7); r0 is 64-aligned
        *(u16x8*)(XnT + (size_t)(c0 + c) * N_ROWS + r0 + ((rg ^ (c & 7)) << 3)) = pk;
    }
}

// ---------------------------------------------------------------------------
// W1T[h][j] = bf16(W1[j][h])  (16 x 1024), unswizzled (only zgemm reads it).
__global__ __launch_bounds__(256) void prep_w1t_k(const float* __restrict__ W1,
        ushort* __restrict__ W1T) {
    int idx = blockIdx.x * 256 + threadIdx.x;   // 16384 total
    int h = idx >> 10, j = idx & 1023;
    W1T[idx] = f2bf(W1[j * HID + h]);
}

// ---------------------------------------------------------------------------
// z[m][h] = sum_k Xb[m][k]*W1T[h][k] + b1[h].  Xb is k-group swizzled by (m&7).
__global__ __launch_bounds__(256) void zgemm_k(const ushort* __restrict__ Xb,
        const ushort* __restrict__ W1T, const float* __restrict__ b1,
        float* __restrict__ z) {
    int t = threadIdx.x;
    int wave = t >> 6, lane = t & 63;
    int rl = lane & 15, q = lane >> 4;
    int rowbase = blockIdx.x * 64 + wave * 16;
    int m = rowbase + rl;
    int msw = m & 7;
    const ushort* arow = Xb + (size_t)m * DIM;
    const ushort* brow = W1T + (size_t)rl * DIM + q * 8;
    f32x4 acc = {0.f, 0.f, 0.f, 0.f};
#pragma unroll 8
    for (int kt = 0; kt < DIM; kt += 32) {
        int gl = ((kt >> 3) & 7) | q;                    // logical group
        int off = (kt & ~63) + ((gl ^ msw) << 3);        // swizzled offset
        bf16x8 a = *(const bf16x8*)(arow + off);
        bf16x8 b = *(const bf16x8*)(brow + kt);
        acc = __builtin_amdgcn_mfma_f32_16x16x32_bf16(a, b, acc, 0, 0, 0);
    }
#pragma unroll
    for (int rg = 0; rg < 4; ++rg) {
        int mm = rowbase + q * 4 + rg;
        z[(size_t)mm * HID + rl] = acc[rg] + b1[rl];
    }
}

// ---------------------------------------------------------------------------
// Per row: h = relu(z); logits = h@W2 + b2; softmax -> P (bf16, swizzled by m&7)
// + PT (bf16, swizzled by o&7), or (do_softmax=0) write logits f32 to out.
__global__ __launch_bounds__(256) void head_k(const float* __restrict__ z,
        const float* __restrict__ W2, const float* __restrict__ b2,
        ushort* __restrict__ P, ushort* __restrict__ PT,
        float* __restrict__ out, int do_softmax) {
    __shared__ float w2s[HID * OUTD];
    __shared__ float b2s[OUTD];
    int t = threadIdx.x;
    ((float4*)w2s)[t] = ((const float4*)W2)[t];   // 1024 floats
    if (t < OUTD) b2s[t] = b2[t];
    __syncthreads();
    int m = blockIdx.x * 256 + t;
    float h[HID];
    const float4* zp = (const float4*)(z + (size_t)m * HID);
#pragma unroll
    for (int i = 0; i < 4; ++i) {
        float4 v = zp[i];
        h[i * 4 + 0] = fmaxf(v.x, 0.f); h[i * 4 + 1] = fmaxf(v.y, 0.f);
        h[i * 4 + 2] = fmaxf(v.z, 0.f); h[i * 4 + 3] = fmaxf(v.w, 0.f);
    }
    float lo[OUTD];
#pragma unroll
    for (int o = 0; o < OUTD; ++o) lo[o] = b2s[o];
    for (int i = 0; i < HID; ++i) {
        float hv = h[i];
#pragma unroll
        for (int o = 0; o < OUTD; ++o) lo[o] += hv * w2s[i * OUTD + o];
    }
    if (do_softmax) {
        float mx = lo[0];
#pragma unroll
        for (int o = 1; o < OUTD; ++o) mx = fmaxf(mx, lo[o]);
        float sm = 0.f;
#pragma unroll
        for (int o = 0; o < OUTD; ++o) { float e = __expf(lo[o] - mx); lo[o] = e; sm += e; }
        float inv = 1.0f / sm;
#pragma unroll
        for (int o8 = 0; o8 < 8; ++o8) {            // P row m: store group o8 at o8^(m&7)
            u16x8 pk;
#pragma unroll
            for (int u = 0; u < 8; ++u) pk[u] = f2bf(lo[o8 * 8 + u] * inv);
            ((u16x8*)(P + (size_t)m * OUTD))[o8 ^ (m & 7)] = pk;
        }
#pragma unroll
        for (int o = 0; o < OUTD; ++o) {            // PT row o, element m, swizzle o&7
            int idx = (m & ~63) + (((((m >> 3) & 7)) ^ (o & 7)) << 3) + (m & 7);
            PT[(size_t)o * N_ROWS + idx] = f2bf(lo[o] * inv);
        }
    } else {
        float4* op = (float4*)(out + (size_t)m * OUTD);
#pragma unroll
        for (int o4 = 0; o4 < 16; ++o4) {
            float4 v; v.x = lo[o4 * 4 + 0]; v.y = lo[o4 * 4 + 1];
            v.z = lo[o4 * 4 + 2]; v.w = lo[o4 * 4 + 3];
            op[o4] = v;
        }
    }
}

// ---------------------------------------------------------------------------
// Cast G_f32 (negated, k-swizzled) and PtXT_f32 (contiguous after it, k-swizzled)
// to bf16. One thread per 16B output group.
__global__ __launch_bounds__(256) void castgp_k(const float* __restrict__ Gf,
        ushort* __restrict__ Gb, ushort* __restrict__ PtXTb,
        const float* __restrict__ PtXTf) {
    int g = blockIdx.x * 256 + threadIdx.x;         // 0 .. 139263
    const int GG = DIM * DIM / 8;                   // 131072 G groups
    const float* src; ushort* dst; float sc;
    if (g < GG) {
        int row = g >> 7;                           // k = 1024 -> 128 groups/row
        int cg = g & 127, tile = cg >> 3, q = cg & 7;
        src = Gf + (size_t)row * DIM + tile * 64 + ((q ^ (row & 7)) << 3);
        dst = Gb + (size_t)g * 8;
        sc = -1.0f;
    } else {
        int gg = g - GG;                            // PtXT: 1024 rows x 64 k (8 groups)
        int row = gg >> 3, q = gg & 7;
        src = PtXTf + (size_t)row * OUTD + ((q ^ (row & 7)) << 3);
        dst = PtXTb + (size_t)gg * 8;
        sc = 1.0f;
    }
    float4 v0 = *(const float4*)src;
    float4 v1 = *(const float4*)(src + 4);
    u16x8 o;
    o[0] = f2bf(v0.x * sc); o[1] = f2bf(v0.y * sc);
    o[2] = f2bf(v0.z * sc); o[3] = f2bf(v0.w * sc);
    o[4] = f2bf(v1.x * sc); o[5] = f2bf(v1.y * sc);
    o[6] = f2bf(v1.z * sc); o[7] = f2bf(v1.w * sc);
    *(u16x8*)dst = o;
}

// ---------------------------------------------------------------------------
// NT MFMA GEMM: C[m][n] (+)= sum_k A[m][k]*B[n][k] over up to 2 segments.
// All bf16 operands are stored pre-swizzled (storage group p = logical p^(row&7)
// within each 64-k tile), so global_load_lds does a straight linear copy and the
// LDS tile has the same invariant R1's fragment reader used (0 bank conflicts).
// Seg0 supports split-K via blockIdx.z. EPI 0: atomicAdd f32 C (pre-zeroed).
// EPI 1: X[m][n] = X[m][n]*rinv[m] + gamma*acc (in-place update epilogue).
template<int BM, int BN, int EPI>
__global__ __launch_bounds__(256) void gemm_nt_k(
        const ushort* __restrict__ A0, int lda0,
        const ushort* __restrict__ B0, int ldb0, int k0len,
        const ushort* __restrict__ A1, int lda1,
        const ushort* __restrict__ B1, int ldb1, int k1len,
        float* __restrict__ C, int ldc,
        const float* __restrict__ rinv, float gamma) {
    constexpr int WTN = BN / 2;
    constexpr int NF = WTN / 16;
    constexpr int NCHUNK = (BM + BN) / 8;   // 1KB chunks (8 rows of 64 k each)
    constexpr int CPW = NCHUNK / 4;         // chunks per wave
    __shared__ ushort ls[(BM + BN) * 64];   // lsA then lsB, contiguous
    ushort* lsA = ls;
    ushort* lsB = ls + BM * 64;
    int t = threadIdx.x;
    int wave = t >> 6, lane = t & 63;
    int rl = lane & 15, q = lane >> 4;
    int wm = wave & 1, wn = wave >> 1;
    int m0 = blockIdx.x * BM, n0 = blockIdx.y * BN;
    int lrow8 = lane >> 3, lgrp = lane & 7;  // staging: lane covers row-sub, group

    f32x4 acc[4][NF];
#pragma unroll
    for (int i = 0; i < 4; ++i)
#pragma unroll
        for (int j = 0; j < NF; ++j) acc[i][j] = f32x4{0.f, 0.f, 0.f, 0.f};

    for (int seg = 0; seg < 2; ++seg) {
        const ushort* A = seg ? A1 : A0;
        const ushort* B = seg ? B1 : B0;
        int lda = seg ? lda1 : lda0;
        int ldb = seg ? ldb1 : ldb0;
        int kb = seg ? 0 : (int)blockIdx.z * k0len;
        int klen = seg ? k1len : k0len;
        if (klen == 0) continue;
        for (int kt = 0; kt < klen; kt += 64) {
            // async stage (BM+BN) x 64 bf16: each wave DMAs CPW KB, lane->base+lane*16
#pragma unroll
            for (int c = 0; c < CPW; ++c) {
                int chunk = wave * CPW + c;
                int row = chunk * 8 + lrow8;
                const ushort* src = (row < BM)
                    ? A + (size_t)(m0 + row) * lda + kb + kt + lgrp * 8
                    : B + (size_t)(n0 + row - BM) * ldb + kb + kt + lgrp * 8;
                __builtin_amdgcn_global_load_lds(AS1C(src), AS3(ls + chunk * 512),
                                                 16, 0, 0);
            }
            __syncthreads();   // drains vmcnt (global_load_lds) + barrier
#pragma unroll
            for (int s = 0; s < 2; ++s) {
                bf16x8 af[4], bfr[NF];
#pragma unroll
                for (int i = 0; i < 4; ++i) {
                    int row = wm * 64 + i * 16 + rl;
                    int sg = ((s << 2) | q) ^ (row & 7);
                    af[i] = *(const bf16x8*)&lsA[row * 64 + sg * 8];
                }
#pragma unroll
                for (int j = 0; j < NF; ++j) {
                    int row = wn * WTN + j * 16 + rl;
                    int sg = ((s << 2) | q) ^ (row & 7);
                    bfr[j] = *(const bf16x8*)&lsB[row * 64 + sg * 8];
                }
#pragma unroll
                for (int i = 0; i < 4; ++i)
#pragma unroll
                    for (int j = 0; j < NF; ++j)
                        acc[i][j] = __builtin_amdgcn_mfma_f32_16x16x32_bf16(
                            af[i], bfr[j], acc[i][j], 0, 0, 0);
            }
            __syncthreads();
        }
    }

#pragma unroll
    for (int i = 0; i < 4; ++i)
#pragma unroll
        for (int j = 0; j < NF; ++j)
#pragma unroll
            for (int rg = 0; rg < 4; ++rg) {
                int m = m0 + wm * 64 + i * 16 + q * 4 + rg;
                int n = n0 + wn * WTN + j * 16 + rl;
                float v = acc[i][j][rg];
                if (EPI == 0) {
                    atomicAdd(&C[(size_t)m * ldc + n], v);
                } else {
                    size_t idx = (size_t)m * ldc + n;
                    C[idx] = C[idx] * rinv[m] + gamma * v;
                }
            }
}

// ---------------------------------------------------------------------------
extern "C" void kernel_launch(void* const* d_in, const int* in_sizes, int n_in,
                              void* d_out, int out_size, void* d_ws, size_t ws_size,
                              hipStream_t stream) {
    float* X = (float*)d_in[0];                 // f32 master X, updated in place
    const float* W1 = (const float*)d_in[1];
    const float* b1 = (const float*)d_in[2];
    const float* W2 = (const float*)d_in[3];
    const float* b2 = (const float*)d_in[4];
    float* out = (float*)d_out;
    char* ws = (char*)d_ws;

    constexpr size_t O_Xnb   = 0;                                     // 33,554,432 B
    constexpr size_t O_XnT   = O_Xnb + (size_t)N_ROWS * DIM * 2;      // 33,554,432
    constexpr size_t O_Pb    = O_XnT + (size_t)DIM * N_ROWS * 2;      //  2,097,152
    constexpr size_t O_PTb   = O_Pb + (size_t)N_ROWS * OUTD * 2;      //  2,097,152
    constexpr size_t O_Gf    = O_PTb + (size_t)OUTD * N_ROWS * 2;     //  4,194,304
    constexpr size_t O_PtXTf = O_Gf + (size_t)DIM * DIM * 4;          //    262,144
    constexpr size_t O_Gb    = O_PtXTf + (size_t)DIM * OUTD * 4;      //  2,097,152
    constexpr size_t O_PtXTb = O_Gb + (size_t)DIM * DIM * 2;          //    131,072
    constexpr size_t O_rinv  = O_PtXTb + (size_t)DIM * OUTD * 2;      //     65,536
    constexpr size_t O_z     = O_rinv + (size_t)N_ROWS * 4;           //  1,048,576
    constexpr size_t O_W1T   = O_z + (size_t)N_ROWS * HID * 4;        //     32,768
    // total ~79.1 MB

    ushort* Xnb   = (ushort*)(ws + O_Xnb);
    ushort* XnT   = (ushort*)(ws + O_XnT);
    ushort* Pb    = (ushort*)(ws + O_Pb);
    ushort* PTb   = (ushort*)(ws + O_PTb);
    float*  Gf    = (float*)(ws + O_Gf);       // PtXTf contiguous after Gf
    ushort* Gb    = (ushort*)(ws + O_Gb);
    ushort* PtXTb = (ushort*)(ws + O_PtXTb);
    float*  riv   = (float*)(ws + O_rinv);
    float*  z     = (float*)(ws + O_z);
    ushort* W1T   = (ushort*)(ws + O_W1T);
    float*  PtXTf = (float*)(ws + O_PtXTf);
    (void)in_sizes; (void)n_in; (void)out_size; (void)ws_size;

    prep_w1t_k<<<64, 256, 0, stream>>>(W1, W1T);

    for (int it = 0; it < DEPTH; ++it) {
        rownorm_k<<<N_ROWS, 256, 0, stream>>>(X, riv, Xnb, 1);
        transpose_k<<<dim3(N_ROWS / 64, DIM / 64), 256, 0, stream>>>(X, riv, XnT);
        zgemm_k<<<N_ROWS / 64, 256, 0, stream>>>(Xnb, W1T, b1, z);
        head_k<<<N_ROWS / 256, 256, 0, stream>>>(z, W2, b2, Pb, PTb, nullptr, 1);
        hipMemsetAsync(Gf, 0, (size_t)(DIM * DIM + DIM * OUTD) * sizeof(float), stream);
        // G = XnT . XnT^T  (split-K 16 -> 1024 blocks, 4/CU)
        gemm_nt_k<128, 128, 0><<<dim3(8, 8, 16), 256, 0, stream>>>(
            XnT, N_ROWS, XnT, N_ROWS, 1024,
            nullptr, 0, nullptr, 0, 0,
            Gf, DIM, nullptr, 0.f);
        // PtX^T = XnT . PT^T  (split-K 64 -> 512 blocks)
        gemm_nt_k<128, 64, 0><<<dim3(8, 1, 64), 256, 0, stream>>>(
            XnT, N_ROWS, PTb, N_ROWS, 256,
            nullptr, 0, nullptr, 0, 0,
            PtXTf, OUTD, nullptr, 0.f);
        castgp_k<<<(DIM * DIM + DIM * OUTD) / 8 / 256, 256, 0, stream>>>(
            Gf, Gb, PtXTb, PtXTf);
        // X = Xn + gamma*(P @ PtX) - gamma*(Xn @ G)   [G sign folded into Gb]
        gemm_nt_k<128, 128, 1><<<dim3(N_ROWS / 128, DIM / 128, 1), 256, 0, stream>>>(
            Pb, OUTD, PtXTb, OUTD, OUTD,
            Xnb, DIM, Gb, DIM, DIM,
            X, DIM, riv, GAMMA);
    }

    // final: out = relu(X@W1 + b1) @ W2 + b2  (unnormalized X)
    rownorm_k<<<N_ROWS, 256, 0, stream>>>(X, riv, Xnb, 0);
    zgemm_k<<<N_ROWS / 64, 256, 0, stream>>>(Xnb, W1T, b1, z);
    head_k<<<N_ROWS / 256, 256, 0, stream>>>(z, W2, b2, nullptr, nullptr, out, 0);
}

// Round 4
// 1235.341 us; speedup vs baseline: 1.3567x; 1.2128x over previous
//
#include <hip/hip_runtime.h>

// CKAFormer R4 (revert-and-refine from proven R2; fp8 R3 abandoned):
// - Master X kept as bf16 (64-k-tile XOR-swizzled, R2-proven layout) in ws,
//   ping-ponged between two 32MB buffers: update gemm reads buffer A, writes
//   buffer B (which held XnT, dead by then) -> no read/write race.
// - No Xnb: zgemm + update-gemm seg0 read unnormalized master; rinv[m] is
//   folded per output row (zgemm epilogue; update scales acc between segments).
// - G = Xn^T Xn: only 36/64 upper-triangle 128x128 tiles (TRI), split-K 16,
//   atomics; castgp mirror-reads G[min][max].
// - All GEMMs: bf16 MFMA 16x16x32, global_load_lds 16B staging into
//   pre-swizzled layouts (R2-verified: 0 LDS bank conflicts).

#define N_ROWS 16384
#define DIM 1024
#define HID 16
#define OUTD 64
#define DEPTH 6
#define GAMMA 1e-4f

typedef short bf16x8 __attribute__((ext_vector_type(8)));
typedef unsigned short u16x8 __attribute__((ext_vector_type(8)));
typedef float f32x4 __attribute__((ext_vector_type(4)));

#define AS1C(p) ((const __attribute__((address_space(1))) void*)(p))
#define AS3(p)  ((__attribute__((address_space(3))) void*)(p))

__device__ __forceinline__ unsigned short f2bf(float f) {
    unsigned u = __builtin_bit_cast(unsigned, f);
    u += 0x7fffu + ((u >> 16) & 1u);   // round-to-nearest-even
    return (unsigned short)(u >> 16);
}
__device__ __forceinline__ float b2f(ushort u) {
    unsigned x = ((unsigned)u) << 16;
    return __builtin_bit_cast(float, x);
}
// stored offset of logical element n within a swizzled row keyed by (row&7)
__device__ __forceinline__ int swz(int n, int row) {
    return (n & ~63) | ((((n >> 3) & 7) ^ (row & 7)) << 3) | (n & 7);
}

// ---------------------------------------------------------------------------
// Once per launch: master Xm = bf16(X), swizzled rows. (R2 rowcast, proven.)
__global__ __launch_bounds__(256) void tobf16_k(const float* __restrict__ X,
        ushort* __restrict__ Xm) {
    int row = blockIdx.x, t = threadIdx.x;
    float4 v = ((const float4*)(X + (size_t)row * DIM))[t];
    ushort4 o4;
    o4.x = f2bf(v.x); o4.y = f2bf(v.y); o4.z = f2bf(v.z); o4.w = f2bf(v.w);
    *(ushort4*)(Xm + (size_t)row * DIM + swz(t * 4, row)) = o4;
}

// ---------------------------------------------------------------------------
// rinv[row] = 1/||Xm[row]||. 2 rows per 256-thread block; storage order is
// irrelevant for the norm.
__global__ __launch_bounds__(256) void rownorm_k(const ushort* __restrict__ Xm,
        float* __restrict__ rinv) {
    int t = threadIdx.x;
    int row = blockIdx.x * 2 + (t >> 7);
    int tid = t & 127;
    const ushort* p = Xm + (size_t)row * DIM + tid * 8;
    u16x8 a = *(const u16x8*)p;
    float ss = 0.f;
#pragma unroll
    for (int u = 0; u < 8; ++u) { float f = b2f(a[u]); ss += f * f; }
    for (int o = 32; o > 0; o >>= 1) ss += __shfl_down(ss, o);
    __shared__ float wsum[4];
    if ((t & 63) == 0) wsum[t >> 6] = ss;
    __syncthreads();
    float tot = (t < 128) ? (wsum[0] + wsum[1]) : (wsum[2] + wsum[3]);
    if (tid == 0) rinv[row] = 1.0f / sqrtf(tot);
}

// ---------------------------------------------------------------------------
// XnT[d][k] = bf16(Xm[k][d] * rinv[k]), swizzled by d. LDS 64x65 f32 tile.
__global__ __launch_bounds__(256) void transpose_k(const ushort* __restrict__ Xm,
        const float* __restrict__ rinv, ushort* __restrict__ XnT) {
    int r0 = blockIdx.x * 64;   // source row (k) tile in [0, 16384)
    int c0 = blockIdx.y * 64;   // source col (d) tile in [0, 1024)
    int t = threadIdx.x;
    __shared__ float ts[64 * 65];
    __shared__ float riS[64];
    if (t < 64) riS[t] = rinv[r0 + t];
    __syncthreads();
#pragma unroll
    for (int i = 0; i < 2; ++i) {
        int idx = i * 256 + t;         // 512 tasks: (row, 8-col group)
        int r = idx >> 3, lg = idx & 7;
        int rr = r0 + r;
        const ushort* p = Xm + (size_t)rr * DIM + c0 + ((lg ^ (rr & 7)) << 3);
        u16x8 a = *(const u16x8*)p;
        float s = riS[r];
        float* d = &ts[r * 65 + lg * 8];
#pragma unroll
        for (int u = 0; u < 8; ++u) d[u] = b2f(a[u]) * s;
    }
    __syncthreads();
#pragma unroll
    for (int i = 0; i < 2; ++i) {
        int g = i * 256 + t;
        int c = g >> 3;                // output row = dim index d-local
        int rg = g & 7;                // 8-elem group along k
        u16x8 pk;
#pragma unroll
        for (int u = 0; u < 8; ++u) pk[u] = f2bf(ts[(rg * 8 + u) * 65 + c]);
        *(u16x8*)(XnT + (size_t)(c0 + c) * N_ROWS + r0 + ((rg ^ (c & 7)) << 3)) = pk;
    }
}

// ---------------------------------------------------------------------------
// W1T[h][j] = bf16(W1[j][h])  (16 x 1024), linear.
__global__ __launch_bounds__(256) void prep_w1t_k(const float* __restrict__ W1,
        ushort* __restrict__ W1T) {
    int idx = blockIdx.x * 256 + threadIdx.x;   // 16384 total
    int h = idx >> 10, j = idx & 1023;
    W1T[idx] = f2bf(W1[j * HID + h]);
}

// ---------------------------------------------------------------------------
// z[m][h] = rv[m] * (Xm[m]·W1[:,h]) + b1[h]   (rv=nullptr -> no scale; final).
__global__ __launch_bounds__(256) void zgemm_k(const ushort* __restrict__ Xm,
        const ushort* __restrict__ W1T, const float* __restrict__ b1,
        float* __restrict__ z, const float* __restrict__ rv) {
    int t = threadIdx.x;
    int wave = t >> 6, lane = t & 63;
    int rl = lane & 15, q = lane >> 4;
    int rowbase = blockIdx.x * 64 + wave * 16;
    int m = rowbase + rl;
    int msw = m & 7;
    const ushort* arow = Xm + (size_t)m * DIM;
    const ushort* brow = W1T + (size_t)rl * DIM + q * 8;
    f32x4 acc = {0.f, 0.f, 0.f, 0.f};
#pragma unroll 8
    for (int kt = 0; kt < DIM; kt += 32) {
        int gl = ((kt >> 3) & 7) | q;
        int off = (kt & ~63) + ((gl ^ msw) << 3);
        bf16x8 a = *(const bf16x8*)(arow + off);
        bf16x8 b = *(const bf16x8*)(brow + kt);
        acc = __builtin_amdgcn_mfma_f32_16x16x32_bf16(a, b, acc, 0, 0, 0);
    }
#pragma unroll
    for (int rg = 0; rg < 4; ++rg) {
        int mm = rowbase + q * 4 + rg;
        float s = rv ? rv[mm] : 1.0f;
        z[(size_t)mm * HID + rl] = acc[rg] * s + b1[rl];
    }
}

// ---------------------------------------------------------------------------
// Per row: h = relu(z); logits = h@W2 + b2; softmax -> Pb (swizzled by m&7)
// + PTb (rows o, swizzled by o&7), or (do_softmax=0) logits f32 to out.
__global__ __launch_bounds__(256) void head_k(const float* __restrict__ z,
        const float* __restrict__ W2, const float* __restrict__ b2,
        ushort* __restrict__ Pb, ushort* __restrict__ PTb,
        float* __restrict__ out, int do_softmax) {
    __shared__ float w2s[HID * OUTD];
    __shared__ float b2s[OUTD];
    int t = threadIdx.x;
    ((float4*)w2s)[t] = ((const float4*)W2)[t];
    if (t < OUTD) b2s[t] = b2[t];
    __syncthreads();
    int m = blockIdx.x * 256 + t;
    float h[HID];
    const float4* zp = (const float4*)(z + (size_t)m * HID);
#pragma unroll
    for (int i = 0; i < 4; ++i) {
        float4 v = zp[i];
        h[i * 4 + 0] = fmaxf(v.x, 0.f); h[i * 4 + 1] = fmaxf(v.y, 0.f);
        h[i * 4 + 2] = fmaxf(v.z, 0.f); h[i * 4 + 3] = fmaxf(v.w, 0.f);
    }
    float lo[OUTD];
#pragma unroll
    for (int o = 0; o < OUTD; ++o) lo[o] = b2s[o];
    for (int i = 0; i < HID; ++i) {
        float hv = h[i];
#pragma unroll
        for (int o = 0; o < OUTD; ++o) lo[o] += hv * w2s[i * OUTD + o];
    }
    if (do_softmax) {
        float mx = lo[0];
#pragma unroll
        for (int o = 1; o < OUTD; ++o) mx = fmaxf(mx, lo[o]);
        float sm = 0.f;
#pragma unroll
        for (int o = 0; o < OUTD; ++o) { float e = __expf(lo[o] - mx); lo[o] = e; sm += e; }
        float inv = 1.0f / sm;
#pragma unroll
        for (int o8 = 0; o8 < 8; ++o8) {
            u16x8 pk;
#pragma unroll
            for (int u = 0; u < 8; ++u) pk[u] = f2bf(lo[o8 * 8 + u] * inv);
            ((u16x8*)(Pb + (size_t)m * OUTD))[o8 ^ (m & 7)] = pk;
        }
#pragma unroll
        for (int o = 0; o < OUTD; ++o)
            PTb[(size_t)o * N_ROWS + swz(m, o)] = f2bf(lo[o] * inv);
    } else {
        float4* op = (float4*)(out + (size_t)m * OUTD);
#pragma unroll
        for (int o4 = 0; o4 < 16; ++o4) {
            float4 v; v.x = lo[o4 * 4 + 0]; v.y = lo[o4 * 4 + 1];
            v.z = lo[o4 * 4 + 2]; v.w = lo[o4 * 4 + 3];
            op[o4] = v;
        }
    }
}

// ---------------------------------------------------------------------------
// Gb[n][k] = bf16(-G[min(k,n)][max(k,n)]) swizzled by n (G upper-tri stored);
// PtXTb[d][o] = bf16(PtXTf) swizzled by d. One thread per ushort4.
__global__ __launch_bounds__(256) void castgp_k(const float* __restrict__ Gf,
        const float* __restrict__ PtXTf, ushort* __restrict__ Gb,
        ushort* __restrict__ PtXTb) {
    int idx = blockIdx.x * 256 + threadIdx.x;   // 278528 units
    if (idx < 262144) {
        int n = idx >> 8;
        int so = (idx & 255) * 4;               // stored offset in row n
        int k0 = (so & ~63) | ((((so >> 3) & 7) ^ (n & 7)) << 3) | (so & 7);
        ushort4 o;
        float v0, v1, v2, v3;
        v0 = (k0 + 0 > n) ? Gf[(size_t)n * DIM + k0 + 0] : Gf[(size_t)(k0 + 0) * DIM + n];
        v1 = (k0 + 1 > n) ? Gf[(size_t)n * DIM + k0 + 1] : Gf[(size_t)(k0 + 1) * DIM + n];
        v2 = (k0 + 2 > n) ? Gf[(size_t)n * DIM + k0 + 2] : Gf[(size_t)(k0 + 2) * DIM + n];
        v3 = (k0 + 3 > n) ? Gf[(size_t)n * DIM + k0 + 3] : Gf[(size_t)(k0 + 3) * DIM + n];
        o.x = f2bf(-v0); o.y = f2bf(-v1); o.z = f2bf(-v2); o.w = f2bf(-v3);
        *(ushort4*)(Gb + (size_t)n * DIM + so) = o;
    } else {
        int vv = idx - 262144;                  // 16384 units
        int d = vv >> 4;
        int so = (vv & 15) * 4;
        int k0 = ((((so >> 3) & 7) ^ (d & 7)) << 3) | (so & 7);
        const float* src = PtXTf + (size_t)d * OUTD + k0;
        ushort4 o;
        o.x = f2bf(src[0]); o.y = f2bf(src[1]); o.z = f2bf(src[2]); o.w = f2bf(src[3]);
        *(ushort4*)(PtXTb + (size_t)d * OUTD + so) = o;
    }
}

// ---------------------------------------------------------------------------
// NT MFMA GEMM (R2-proven body): C[m][n] (+)= sum_k A[m][k]*B[n][k], 2 segments.
// Operands pre-swizzled; global_load_lds linear copy; fragments via XOR swizzle.
// TRI=1: blockIdx.x -> upper-triangle 128x128 tile of 8x8 grid (no mirror;
// castgp reads upper). Seg0 split-K via blockIdx.z. EPI 0: atomicAdd f32 C.
// EPI 1: between seg0/seg1 scale acc by rinv[m]; epilogue writes bf16 master:
// C_b[m][n] = bf16( b2f(A0[m][n]) * rinv[m] + gamma*acc ).
template<int BM, int BN, int EPI, int TRI>
__global__ __launch_bounds__(256) void gemm_nt_k(
        const ushort* __restrict__ A0, int lda0,
        const ushort* __restrict__ B0, int ldb0, int k0len,
        const ushort* __restrict__ A1, int lda1,
        const ushort* __restrict__ B1, int ldb1, int k1len,
        float* __restrict__ C, int ldc,
        const float* __restrict__ rinv, float gamma) {
    constexpr int WTN = BN / 2;
    constexpr int NF = WTN / 16;
    constexpr int NCHUNK = (BM + BN) / 8;
    constexpr int CPW = NCHUNK / 4;
    __shared__ ushort ls[(BM + BN) * 64];
    ushort* lsA = ls;
    ushort* lsB = ls + BM * 64;
    int t = threadIdx.x;
    int wave = t >> 6, lane = t & 63;
    int rl = lane & 15, q = lane >> 4;
    int wm = wave & 1, wn = wave >> 1;
    int m0, n0;
    if (TRI) {
        int bx = blockIdx.x, tm = 0;
        while (bx >= 8 - tm) { bx -= 8 - tm; ++tm; }
        m0 = tm * 128; n0 = (tm + bx) * 128;
    } else {
        m0 = blockIdx.x * BM; n0 = blockIdx.y * BN;
    }
    int lrow8 = lane >> 3, lgrp = lane & 7;

    f32x4 acc[4][NF];
#pragma unroll
    for (int i = 0; i < 4; ++i)
#pragma unroll
        for (int j = 0; j < NF; ++j) acc[i][j] = f32x4{0.f, 0.f, 0.f, 0.f};
    float rvv[4][4];

    for (int seg = 0; seg < 2; ++seg) {
        const ushort* A = seg ? A1 : A0;
        const ushort* B = seg ? B1 : B0;
        int lda = seg ? lda1 : lda0;
        int ldb = seg ? ldb1 : ldb0;
        int kb = seg ? 0 : (int)blockIdx.z * k0len;
        int klen = seg ? k1len : k0len;
        if (klen > 0) {
            for (int kt = 0; kt < klen; kt += 64) {
#pragma unroll
                for (int c = 0; c < CPW; ++c) {
                    int chunk = wave * CPW + c;
                    int row = chunk * 8 + lrow8;
                    const ushort* src = (row < BM)
                        ? A + (size_t)(m0 + row) * lda + kb + kt + lgrp * 8
                        : B + (size_t)(n0 + row - BM) * ldb + kb + kt + lgrp * 8;
                    __builtin_amdgcn_global_load_lds(AS1C(src), AS3(ls + chunk * 512),
                                                     16, 0, 0);
                }
                __syncthreads();
#pragma unroll
                for (int s = 0; s < 2; ++s) {
                    bf16x8 af[4], bfr[NF];
#pragma unroll
                    for (int i = 0; i < 4; ++i) {
                        int row = wm * 64 + i * 16 + rl;
                        int sg = ((s << 2) | q) ^ (row & 7);
                        af[i] = *(const bf16x8*)&lsA[row * 64 + sg * 8];
                    }
#pragma unroll
                    for (int j = 0; j < NF; ++j) {
                        int row = wn * WTN + j * 16 + rl;
                        int sg = ((s << 2) | q) ^ (row & 7);
                        bfr[j] = *(const bf16x8*)&lsB[row * 64 + sg * 8];
                    }
#pragma unroll
                    for (int i = 0; i < 4; ++i)
#pragma unroll
                        for (int j = 0; j < NF; ++j)
                            acc[i][j] = __builtin_amdgcn_mfma_f32_16x16x32_bf16(
                                af[i], bfr[j], acc[i][j], 0, 0, 0);
                }
                __syncthreads();
            }
        }
        // fold rinv[m] into the seg0 (Xm·-G) partial; seg1 (P·PtX) stays unscaled
        if (EPI == 1 && seg == 0) {
#pragma unroll
            for (int i = 0; i < 4; ++i)
#pragma unroll
                for (int rg = 0; rg < 4; ++rg)
                    rvv[i][rg] = rinv[m0 + wm * 64 + i * 16 + q * 4 + rg];
#pragma unroll
            for (int i = 0; i < 4; ++i)
#pragma unroll
                for (int j = 0; j < NF; ++j)
#pragma unroll
                    for (int rg = 0; rg < 4; ++rg)
                        acc[i][j][rg] *= rvv[i][rg];
        }
    }

#pragma unroll
    for (int i = 0; i < 4; ++i)
#pragma unroll
        for (int j = 0; j < NF; ++j)
#pragma unroll
            for (int rg = 0; rg < 4; ++rg) {
                int m = m0 + wm * 64 + i * 16 + q * 4 + rg;
                int n = n0 + wn * WTN + j * 16 + rl;
                float v = acc[i][j][rg];
                if (EPI == 0) {
                    atomicAdd(&C[(size_t)m * ldc + n], v);
                } else {
                    int so = swz(n, m);
                    float base = b2f(A0[(size_t)m * lda0 + so]);
                    ((ushort*)C)[(size_t)m * ldc + so] =
                        f2bf(base * rvv[i][rg] + gamma * v);
                }
            }
}

// ---------------------------------------------------------------------------
extern "C" void kernel_launch(void* const* d_in, const int* in_sizes, int n_in,
                              void* d_out, int out_size, void* d_ws, size_t ws_size,
                              hipStream_t stream) {
    const float* X = (const float*)d_in[0];
    const float* W1 = (const float*)d_in[1];
    const float* b1 = (const float*)d_in[2];
    const float* W2 = (const float*)d_in[3];
    const float* b2 = (const float*)d_in[4];
    float* out = (float*)d_out;
    char* ws = (char*)d_ws;

    constexpr size_t O_BufA  = 0;                                     // 33,554,432
    constexpr size_t O_BufB  = O_BufA + (size_t)N_ROWS * DIM * 2;     // 33,554,432
    constexpr size_t O_Pb    = O_BufB + (size_t)N_ROWS * DIM * 2;     //  2,097,152
    constexpr size_t O_PTb   = O_Pb + (size_t)N_ROWS * OUTD * 2;      //  2,097,152
    constexpr size_t O_Gf    = O_PTb + (size_t)OUTD * N_ROWS * 2;     //  4,194,304
    constexpr size_t O_PtXTf = O_Gf + (size_t)DIM * DIM * 4;          //    262,144
    constexpr size_t O_Gb    = O_PtXTf + (size_t)DIM * OUTD * 4;      //  2,097,152
    constexpr size_t O_PtXTb = O_Gb + (size_t)DIM * DIM * 2;          //    131,072
    constexpr size_t O_riv   = O_PtXTb + (size_t)DIM * OUTD * 2;      //     65,536
    constexpr size_t O_z     = O_riv + (size_t)N_ROWS * 4;            //  1,048,576
    constexpr size_t O_W1T   = O_z + (size_t)N_ROWS * HID * 4;        //     32,768
    // total 79,134,720 B — identical to the proven R1/R2 footprint

    ushort* bufA  = (ushort*)(ws + O_BufA);
    ushort* bufB  = (ushort*)(ws + O_BufB);
    ushort* Pb    = (ushort*)(ws + O_Pb);
    ushort* PTb   = (ushort*)(ws + O_PTb);
    float*  Gf    = (float*)(ws + O_Gf);
    float*  PtXTf = (float*)(ws + O_PtXTf);
    ushort* Gb    = (ushort*)(ws + O_Gb);
    ushort* PtXTb = (ushort*)(ws + O_PtXTb);
    float*  riv   = (float*)(ws + O_riv);
    float*  z     = (float*)(ws + O_z);
    ushort* W1T   = (ushort*)(ws + O_W1T);
    (void)in_sizes; (void)n_in; (void)out_size; (void)ws_size;

    prep_w1t_k<<<64, 256, 0, stream>>>(W1, W1T);
    tobf16_k<<<N_ROWS, 256, 0, stream>>>(X, bufA);

    ushort* xm  = bufA;   // current master X_t (bf16, swizzled rows)
    ushort* alt = bufB;   // scratch: XnT during iter, then becomes X_{t+1}

    for (int it = 0; it < DEPTH; ++it) {
        rownorm_k<<<N_ROWS / 2, 256, 0, stream>>>(xm, riv);
        transpose_k<<<dim3(N_ROWS / 64, DIM / 64), 256, 0, stream>>>(xm, riv, alt);
        zgemm_k<<<N_ROWS / 64, 256, 0, stream>>>(xm, W1T, b1, z, riv);
        head_k<<<N_ROWS / 256, 256, 0, stream>>>(z, W2, b2, Pb, PTb, nullptr, 1);
        hipMemsetAsync(Gf, 0, (size_t)(DIM * DIM + DIM * OUTD) * sizeof(float), stream);
        // G = XnT . XnT^T : 36 upper-triangle tiles, split-K 16
        gemm_nt_k<128, 128, 0, 1><<<dim3(36, 1, 16), 256, 0, stream>>>(
            alt, N_ROWS, alt, N_ROWS, 1024,
            nullptr, 0, nullptr, 0, 0,
            Gf, DIM, nullptr, 0.f);
        // PtX^T[d][o] = XnT . PTb^T : split-K 64
        gemm_nt_k<128, 64, 0, 0><<<dim3(8, 1, 64), 256, 0, stream>>>(
            alt, N_ROWS, PTb, N_ROWS, 256,
            nullptr, 0, nullptr, 0, 0,
            PtXTf, OUTD, nullptr, 0.f);
        castgp_k<<<1088, 256, 0, stream>>>(Gf, PtXTf, Gb, PtXTb);
        // X_{t+1}[m][n] = Xn + g*(P@PtX - Xn@G):
        //   seg0 = Xm·(-G) (scaled by rinv[m] after), seg1 = P·PtX; epilogue
        //   base = Xm[m][n]*rinv[m]; OUTPUT into `alt` (XnT now dead) -> no race
        gemm_nt_k<128, 128, 1, 0><<<dim3(N_ROWS / 128, DIM / 128, 1), 256, 0, stream>>>(
            xm, DIM, Gb, DIM, 1024,
            Pb, OUTD, PtXTb, OUTD, OUTD,
            (float*)alt, DIM, riv, GAMMA);
        ushort* tmp = xm; xm = alt; alt = tmp;   // ping-pong
    }

    // final: out = relu(X@W1 + b1) @ W2 + b2  (unnormalized master, rv=nullptr)
    zgemm_k<<<N_ROWS / 64, 256, 0, stream>>>(xm, W1T, b1, z, nullptr);
    head_k<<<N_ROWS / 256, 256, 0, stream>>>(z, W2, b2, Pb, PTb, out, 0);
}

// Round 5
// 1121.151 us; speedup vs baseline: 1.4949x; 1.1019x over previous
//
#include <hip/hip_runtime.h>

// CKAFormer R5 (from proven R4):
// - gemm_nt_k: __launch_bounds__(256,3) targeting 3 blocks/CU (R4 measured 2);
//   staging restructured to per-wave static A/B role with hoisted base pointers
//   (waves 0..BM/64-1 stage A, next BN/64 stage B) — removes per-chunk ternary.
// - rownorm pass eliminated: update-gemm epilogue accumulates row sum-of-squares
//   of X_{t+1} (shuffle-reduce + atomicAdd into ssacc), tiny rsqrt_k -> rinv.
//   ssacc aliases PtXTf[0:16384] (dead after castgp; castgp zeroes it post-read).
// - tobf16_k computes rinv for iter 0 directly (full row per block).
// - Everything else: R4-proven (bf16 ping-pong master, TRI G, swizzled layouts,
//   global_load_lds 16B staging, 0 LDS bank conflicts).

#define N_ROWS 16384
#define DIM 1024
#define HID 16
#define OUTD 64
#define DEPTH 6
#define GAMMA 1e-4f

typedef short bf16x8 __attribute__((ext_vector_type(8)));
typedef unsigned short u16x8 __attribute__((ext_vector_type(8)));
typedef float f32x4 __attribute__((ext_vector_type(4)));

#define AS1C(p) ((const __attribute__((address_space(1))) void*)(p))
#define AS3(p)  ((__attribute__((address_space(3))) void*)(p))

__device__ __forceinline__ unsigned short f2bf(float f) {
    unsigned u = __builtin_bit_cast(unsigned, f);
    u += 0x7fffu + ((u >> 16) & 1u);   // round-to-nearest-even
    return (unsigned short)(u >> 16);
}
__device__ __forceinline__ float b2f(ushort u) {
    unsigned x = ((unsigned)u) << 16;
    return __builtin_bit_cast(float, x);
}
// stored offset of logical element n within a swizzled row keyed by (row&7)
__device__ __forceinline__ int swz(int n, int row) {
    return (n & ~63) | ((((n >> 3) & 7) ^ (row & 7)) << 3) | (n & 7);
}

// ---------------------------------------------------------------------------
// Once per launch: master Xm = bf16(X) swizzled rows + rinv[row] = 1/||X[row]||.
__global__ __launch_bounds__(256) void tobf16_k(const float* __restrict__ X,
        ushort* __restrict__ Xm, float* __restrict__ rinv) {
    int row = blockIdx.x, t = threadIdx.x;
    float4 v = ((const float4*)(X + (size_t)row * DIM))[t];
    ushort4 o4;
    o4.x = f2bf(v.x); o4.y = f2bf(v.y); o4.z = f2bf(v.z); o4.w = f2bf(v.w);
    *(ushort4*)(Xm + (size_t)row * DIM + swz(t * 4, row)) = o4;
    float ss = v.x * v.x + v.y * v.y + v.z * v.z + v.w * v.w;
    for (int o = 32; o > 0; o >>= 1) ss += __shfl_down(ss, o);
    __shared__ float wsum[4];
    if ((t & 63) == 0) wsum[t >> 6] = ss;
    __syncthreads();
    if (t == 0) rinv[row] = 1.0f / sqrtf(wsum[0] + wsum[1] + wsum[2] + wsum[3]);
}

// ---------------------------------------------------------------------------
// rinv[i] = 1/sqrt(ssacc[i]).  (ssacc zeroing handled by castgp/memset.)
__global__ __launch_bounds__(256) void rsqrt_k(const float* __restrict__ ssacc,
        float* __restrict__ rinv) {
    int i = blockIdx.x * 256 + threadIdx.x;
    rinv[i] = 1.0f / sqrtf(ssacc[i]);
}

// ---------------------------------------------------------------------------
// XnT[d][k] = bf16(Xm[k][d] * rinv[k]), swizzled by d. LDS 64x65 f32 tile.
__global__ __launch_bounds__(256) void transpose_k(const ushort* __restrict__ Xm,
        const float* __restrict__ rinv, ushort* __restrict__ XnT) {
    int r0 = blockIdx.x * 64;   // source row (k) tile
    int c0 = blockIdx.y * 64;   // source col (d) tile
    int t = threadIdx.x;
    __shared__ float ts[64 * 65];
    __shared__ float riS[64];
    if (t < 64) riS[t] = rinv[r0 + t];
    __syncthreads();
#pragma unroll
    for (int i = 0; i < 2; ++i) {
        int idx = i * 256 + t;
        int r = idx >> 3, lg = idx & 7;
        int rr = r0 + r;
        const ushort* p = Xm + (size_t)rr * DIM + c0 + ((lg ^ (rr & 7)) << 3);
        u16x8 a = *(const u16x8*)p;
        float s = riS[r];
        float* d = &ts[r * 65 + lg * 8];
#pragma unroll
        for (int u = 0; u < 8; ++u) d[u] = b2f(a[u]) * s;
    }
    __syncthreads();
#pragma unroll
    for (int i = 0; i < 2; ++i) {
        int g = i * 256 + t;
        int c = g >> 3;
        int rg = g & 7;
        u16x8 pk;
#pragma unroll
        for (int u = 0; u < 8; ++u) pk[u] = f2bf(ts[(rg * 8 + u) * 65 + c]);
        *(u16x8*)(XnT + (size_t)(c0 + c) * N_ROWS + r0 + ((rg ^ (c & 7)) << 3)) = pk;
    }
}

// ---------------------------------------------------------------------------
__global__ __launch_bounds__(256) void prep_w1t_k(const float* __restrict__ W1,
        ushort* __restrict__ W1T) {
    int idx = blockIdx.x * 256 + threadIdx.x;   // 16384
    int h = idx >> 10, j = idx & 1023;
    W1T[idx] = f2bf(W1[j * HID + h]);
}

// ---------------------------------------------------------------------------
// z[m][h] = rv[m] * (Xm[m]·W1[:,h]) + b1[h]   (rv=nullptr -> no scale; final).
__global__ __launch_bounds__(256) void zgemm_k(const ushort* __restrict__ Xm,
        const ushort* __restrict__ W1T, const float* __restrict__ b1,
        float* __restrict__ z, const float* __restrict__ rv) {
    int t = threadIdx.x;
    int wave = t >> 6, lane = t & 63;
    int rl = lane & 15, q = lane >> 4;
    int rowbase = blockIdx.x * 64 + wave * 16;
    int m = rowbase + rl;
    int msw = m & 7;
    const ushort* arow = Xm + (size_t)m * DIM;
    const ushort* brow = W1T + (size_t)rl * DIM + q * 8;
    f32x4 acc = {0.f, 0.f, 0.f, 0.f};
#pragma unroll 8
    for (int kt = 0; kt < DIM; kt += 32) {
        int gl = ((kt >> 3) & 7) | q;
        int off = (kt & ~63) + ((gl ^ msw) << 3);
        bf16x8 a = *(const bf16x8*)(arow + off);
        bf16x8 b = *(const bf16x8*)(brow + kt);
        acc = __builtin_amdgcn_mfma_f32_16x16x32_bf16(a, b, acc, 0, 0, 0);
    }
#pragma unroll
    for (int rg = 0; rg < 4; ++rg) {
        int mm = rowbase + q * 4 + rg;
        float s = rv ? rv[mm] : 1.0f;
        z[(size_t)mm * HID + rl] = acc[rg] * s + b1[rl];
    }
}

// ---------------------------------------------------------------------------
// Per row: h = relu(z); logits = h@W2 + b2; softmax -> Pb (swizzled by m&7)
// + PTb (rows o, swizzled by o&7), or (do_softmax=0) logits f32 to out.
__global__ __launch_bounds__(256) void head_k(const float* __restrict__ z,
        const float* __restrict__ W2, const float* __restrict__ b2,
        ushort* __restrict__ Pb, ushort* __restrict__ PTb,
        float* __restrict__ out, int do_softmax) {
    __shared__ float w2s[HID * OUTD];
    __shared__ float b2s[OUTD];
    int t = threadIdx.x;
    ((float4*)w2s)[t] = ((const float4*)W2)[t];
    if (t < OUTD) b2s[t] = b2[t];
    __syncthreads();
    int m = blockIdx.x * 256 + t;
    float h[HID];
    const float4* zp = (const float4*)(z + (size_t)m * HID);
#pragma unroll
    for (int i = 0; i < 4; ++i) {
        float4 v = zp[i];
        h[i * 4 + 0] = fmaxf(v.x, 0.f); h[i * 4 + 1] = fmaxf(v.y, 0.f);
        h[i * 4 + 2] = fmaxf(v.z, 0.f); h[i * 4 + 3] = fmaxf(v.w, 0.f);
    }
    float lo[OUTD];
#pragma unroll
    for (int o = 0; o < OUTD; ++o) lo[o] = b2s[o];
    for (int i = 0; i < HID; ++i) {
        float hv = h[i];
#pragma unroll
        for (int o = 0; o < OUTD; ++o) lo[o] += hv * w2s[i * OUTD + o];
    }
    if (do_softmax) {
        float mx = lo[0];
#pragma unroll
        for (int o = 1; o < OUTD; ++o) mx = fmaxf(mx, lo[o]);
        float sm = 0.f;
#pragma unroll
        for (int o = 0; o < OUTD; ++o) { float e = __expf(lo[o] - mx); lo[o] = e; sm += e; }
        float inv = 1.0f / sm;
#pragma unroll
        for (int o8 = 0; o8 < 8; ++o8) {
            u16x8 pk;
#pragma unroll
            for (int u = 0; u < 8; ++u) pk[u] = f2bf(lo[o8 * 8 + u] * inv);
            ((u16x8*)(Pb + (size_t)m * OUTD))[o8 ^ (m & 7)] = pk;
        }
#pragma unroll
        for (int o = 0; o < OUTD; ++o)
            PTb[(size_t)o * N_ROWS + swz(m, o)] = f2bf(lo[o] * inv);
    } else {
        float4* op = (float4*)(out + (size_t)m * OUTD);
#pragma unroll
        for (int o4 = 0; o4 < 16; ++o4) {
            float4 v; v.x = lo[o4 * 4 + 0]; v.y = lo[o4 * 4 + 1];
            v.z = lo[o4 * 4 + 2]; v.w = lo[o4 * 4 + 3];
            op[o4] = v;
        }
    }
}

// ---------------------------------------------------------------------------
// Gb[n][k] = bf16(-G[min][max]) swizzled by n; PtXTb[d][o] = bf16(PtXTf)
// swizzled by d. PtXTf elements are ZEROED after reading (the first 16384
// floats double as ssacc for the update gemm's row-sum-of-squares).
__global__ __launch_bounds__(256) void castgp_k(const float* __restrict__ Gf,
        float* __restrict__ PtXTf, ushort* __restrict__ Gb,
        ushort* __restrict__ PtXTb) {
    int idx = blockIdx.x * 256 + threadIdx.x;   // 278528 units
    if (idx < 262144) {
        int n = idx >> 8;
        int so = (idx & 255) * 4;
        int k0 = (so & ~63) | ((((so >> 3) & 7) ^ (n & 7)) << 3) | (so & 7);
        ushort4 o;
        float v0, v1, v2, v3;
        v0 = (k0 + 0 > n) ? Gf[(size_t)n * DIM + k0 + 0] : Gf[(size_t)(k0 + 0) * DIM + n];
        v1 = (k0 + 1 > n) ? Gf[(size_t)n * DIM + k0 + 1] : Gf[(size_t)(k0 + 1) * DIM + n];
        v2 = (k0 + 2 > n) ? Gf[(size_t)n * DIM + k0 + 2] : Gf[(size_t)(k0 + 2) * DIM + n];
        v3 = (k0 + 3 > n) ? Gf[(size_t)n * DIM + k0 + 3] : Gf[(size_t)(k0 + 3) * DIM + n];
        o.x = f2bf(-v0); o.y = f2bf(-v1); o.z = f2bf(-v2); o.w = f2bf(-v3);
        *(ushort4*)(Gb + (size_t)n * DIM + so) = o;
    } else {
        int vv = idx - 262144;                  // 16384 units
        int d = vv >> 4;
        int so = (vv & 15) * 4;
        int k0 = ((((so >> 3) & 7) ^ (d & 7)) << 3) | (so & 7);
        float* src = PtXTf + (size_t)d * OUTD + k0;
        float4 v = *(const float4*)src;
        ushort4 o;
        o.x = f2bf(v.x); o.y = f2bf(v.y); o.z = f2bf(v.z); o.w = f2bf(v.w);
        *(ushort4*)(PtXTb + (size_t)d * OUTD + so) = o;
        *(float4*)src = float4{0.f, 0.f, 0.f, 0.f};   // prep ssacc region
    }
}

// ---------------------------------------------------------------------------
// NT MFMA GEMM. Waves 0..BM/64-1 stage A (64 rows each), next BN/64 waves
// stage B; base pointers hoisted out of the k-loop. TRI=1: upper-triangle
// 128x128 tiles. EPI 0: atomicAdd f32 C. EPI 1: seg0 acc scaled by rinv[m];
// epilogue writes bf16 master C_b = bf16(b2f(A0)*rinv + gamma*acc) and
// accumulates row sum-of-squares into ssacc via shuffle-reduce + atomicAdd.
template<int BM, int BN, int EPI, int TRI>
__global__ __launch_bounds__(256, 3) void gemm_nt_k(
        const ushort* __restrict__ A0, int lda0,
        const ushort* __restrict__ B0, int ldb0, int k0len,
        const ushort* __restrict__ A1, int lda1,
        const ushort* __restrict__ B1, int ldb1, int k1len,
        float* __restrict__ C, int ldc,
        const float* __restrict__ rinv, float gamma,
        float* __restrict__ ssacc) {
    constexpr int WTN = BN / 2;
    constexpr int NF = WTN / 16;
    constexpr int NAW = BM / 64;     // waves staging A
    constexpr int NBW = BN / 64;     // waves staging B
    __shared__ ushort ls[(BM + BN) * 64];
    ushort* lsA = ls;
    ushort* lsB = ls + BM * 64;
    int t = threadIdx.x;
    int wave = t >> 6, lane = t & 63;
    int rl = lane & 15, q = lane >> 4;
    int wm = wave & 1, wn = wave >> 1;
    int m0, n0;
    if (TRI) {
        int bx = blockIdx.x, tm = 0;
        while (bx >= 8 - tm) { bx -= 8 - tm; ++tm; }
        m0 = tm * 128; n0 = (tm + bx) * 128;
    } else {
        m0 = blockIdx.x * BM; n0 = blockIdx.y * BN;
    }
    int lrow8 = lane >> 3, lgrp = lane & 7;
    bool isA = wave < NAW;
    bool active = wave < NAW + NBW;
    int wlocal = isA ? wave : wave - NAW;
    // wave-uniform LDS dest base (ushort units)
    ushort* dstb = ls + (isA ? 0 : BM * 64) + wlocal * 4096;

    f32x4 acc[4][NF];
#pragma unroll
    for (int i = 0; i < 4; ++i)
#pragma unroll
        for (int j = 0; j < NF; ++j) acc[i][j] = f32x4{0.f, 0.f, 0.f, 0.f};
    float rvv[4][4];

    for (int seg = 0; seg < 2; ++seg) {
        int klen = seg ? k1len : k0len;
        if (klen > 0) {
            const ushort* OPA = seg ? A1 : A0;
            const ushort* OPB = seg ? B1 : B0;
            int ldaS = seg ? lda1 : lda0;
            int ldbS = seg ? ldb1 : ldb0;
            int kb = seg ? 0 : (int)blockIdx.z * k0len;
            const ushort* srcb;
            size_t ldS;
            if (isA) {
                srcb = OPA + (size_t)(m0 + wlocal * 64 + lrow8) * ldaS + lgrp * 8;
                ldS = (size_t)ldaS;
            } else {
                srcb = OPB + (size_t)(n0 + wlocal * 64 + lrow8) * ldbS + lgrp * 8;
                ldS = (size_t)ldbS;
            }
            srcb += kb;
            for (int kt = 0; kt < klen; kt += 64) {
                if (active) {
#pragma unroll
                    for (int c = 0; c < 8; ++c)
                        __builtin_amdgcn_global_load_lds(AS1C(srcb + c * 8 * ldS),
                                                         AS3(dstb + c * 512), 16, 0, 0);
                    srcb += 64;
                }
                __syncthreads();
#pragma unroll
                for (int s = 0; s < 2; ++s) {
                    bf16x8 af[4], bfr[NF];
#pragma unroll
                    for (int i = 0; i < 4; ++i) {
                        int row = wm * 64 + i * 16 + rl;
                        int sg = ((s << 2) | q) ^ (row & 7);
                        af[i] = *(const bf16x8*)&lsA[row * 64 + sg * 8];
                    }
#pragma unroll
                    for (int j = 0; j < NF; ++j) {
                        int row = wn * WTN + j * 16 + rl;
                        int sg = ((s << 2) | q) ^ (row & 7);
                        bfr[j] = *(const bf16x8*)&lsB[row * 64 + sg * 8];
                    }
#pragma unroll
                    for (int i = 0; i < 4; ++i)
#pragma unroll
                        for (int j = 0; j < NF; ++j)
                            acc[i][j] = __builtin_amdgcn_mfma_f32_16x16x32_bf16(
                                af[i], bfr[j], acc[i][j], 0, 0, 0);
                }
                __syncthreads();
            }
        }
        if (EPI == 1 && seg == 0) {
#pragma unroll
            for (int i = 0; i < 4; ++i)
#pragma unroll
                for (int rg = 0; rg < 4; ++rg)
                    rvv[i][rg] = rinv[m0 + wm * 64 + i * 16 + q * 4 + rg];
#pragma unroll
            for (int i = 0; i < 4; ++i)
#pragma unroll
                for (int j = 0; j < NF; ++j)
#pragma unroll
                    for (int rg = 0; rg < 4; ++rg)
                        acc[i][j][rg] *= rvv[i][rg];
        }
    }

    if (EPI == 0) {
#pragma unroll
        for (int i = 0; i < 4; ++i)
#pragma unroll
            for (int j = 0; j < NF; ++j)
#pragma unroll
                for (int rg = 0; rg < 4; ++rg) {
                    int m = m0 + wm * 64 + i * 16 + q * 4 + rg;
                    int n = n0 + wn * WTN + j * 16 + rl;
                    atomicAdd(&C[(size_t)m * ldc + n], acc[i][j][rg]);
                }
    } else {
#pragma unroll
        for (int i = 0; i < 4; ++i)
#pragma unroll
            for (int rg = 0; rg < 4; ++rg) {
                int m = m0 + wm * 64 + i * 16 + q * 4 + rg;
                float ssl = 0.f;
#pragma unroll
                for (int j = 0; j < NF; ++j) {
                    int n = n0 + wn * WTN + j * 16 + rl;
                    int so = swz(n, m);
                    float base = b2f(A0[(size_t)m * lda0 + so]);
                    float vf = base * rvv[i][rg] + gamma * acc[i][j][rg];
                    ((ushort*)C)[(size_t)m * ldc + so] = f2bf(vf);
                    ssl += vf * vf;
                }
                ssl += __shfl_xor(ssl, 1);
                ssl += __shfl_xor(ssl, 2);
                ssl += __shfl_xor(ssl, 4);
                ssl += __shfl_xor(ssl, 8);
                if (rl == 0) atomicAdd(&ssacc[m], ssl);
            }
    }
}

// ---------------------------------------------------------------------------
extern "C" void kernel_launch(void* const* d_in, const int* in_sizes, int n_in,
                              void* d_out, int out_size, void* d_ws, size_t ws_size,
                              hipStream_t stream) {
    const float* X = (const float*)d_in[0];
    const float* W1 = (const float*)d_in[1];
    const float* b1 = (const float*)d_in[2];
    const float* W2 = (const float*)d_in[3];
    const float* b2 = (const float*)d_in[4];
    float* out = (float*)d_out;
    char* ws = (char*)d_ws;

    constexpr size_t O_BufA  = 0;                                     // 33,554,432
    constexpr size_t O_BufB  = O_BufA + (size_t)N_ROWS * DIM * 2;     // 33,554,432
    constexpr size_t O_Pb    = O_BufB + (size_t)N_ROWS * DIM * 2;     //  2,097,152
    constexpr size_t O_PTb   = O_Pb + (size_t)N_ROWS * OUTD * 2;      //  2,097,152
    constexpr size_t O_Gf    = O_PTb + (size_t)OUTD * N_ROWS * 2;     //  4,194,304
    constexpr size_t O_PtXTf = O_Gf + (size_t)DIM * DIM * 4;          //    262,144
    constexpr size_t O_Gb    = O_PtXTf + (size_t)DIM * OUTD * 4;      //  2,097,152
    constexpr size_t O_PtXTb = O_Gb + (size_t)DIM * DIM * 2;          //    131,072
    constexpr size_t O_riv   = O_PtXTb + (size_t)DIM * OUTD * 2;      //     65,536
    constexpr size_t O_z     = O_riv + (size_t)N_ROWS * 4;            //  1,048,576
    constexpr size_t O_W1T   = O_z + (size_t)N_ROWS * HID * 4;        //     32,768
    // total 79,134,720 B — identical to proven R1/R2/R4 footprint

    ushort* bufA  = (ushort*)(ws + O_BufA);
    ushort* bufB  = (ushort*)(ws + O_BufB);
    ushort* Pb    = (ushort*)(ws + O_Pb);
    ushort* PTb   = (ushort*)(ws + O_PTb);
    float*  Gf    = (float*)(ws + O_Gf);
    float*  PtXTf = (float*)(ws + O_PtXTf);   // first 16384 floats double as ssacc
    ushort* Gb    = (ushort*)(ws + O_Gb);
    ushort* PtXTb = (ushort*)(ws + O_PtXTb);
    float*  riv   = (float*)(ws + O_riv);
    float*  z     = (float*)(ws + O_z);
    ushort* W1T   = (ushort*)(ws + O_W1T);
    float*  ssacc = PtXTf;
    (void)in_sizes; (void)n_in; (void)out_size; (void)ws_size;

    prep_w1t_k<<<64, 256, 0, stream>>>(W1, W1T);
    tobf16_k<<<N_ROWS, 256, 0, stream>>>(X, bufA, riv);

    ushort* xm  = bufA;   // current master X_t (bf16, swizzled rows)
    ushort* alt = bufB;   // scratch: XnT during iter, then becomes X_{t+1}

    for (int it = 0; it < DEPTH; ++it) {
        transpose_k<<<dim3(N_ROWS / 64, DIM / 64), 256, 0, stream>>>(xm, riv, alt);
        zgemm_k<<<N_ROWS / 64, 256, 0, stream>>>(xm, W1T, b1, z, riv);
        head_k<<<N_ROWS / 256, 256, 0, stream>>>(z, W2, b2, Pb, PTb, nullptr, 1);
        hipMemsetAsync(Gf, 0, (size_t)(DIM * DIM + DIM * OUTD) * sizeof(float), stream);
        // G = XnT . XnT^T : 36 upper-triangle tiles, split-K 16
        gemm_nt_k<128, 128, 0, 1><<<dim3(36, 1, 16), 256, 0, stream>>>(
            alt, N_ROWS, alt, N_ROWS, 1024,
            nullptr, 0, nullptr, 0, 0,
            Gf, DIM, nullptr, 0.f, nullptr);
        // PtX^T[d][o] = XnT . PTb^T : split-K 64
        gemm_nt_k<128, 64, 0, 0><<<dim3(8, 1, 64), 256, 0, stream>>>(
            alt, N_ROWS, PTb, N_ROWS, 256,
            nullptr, 0, nullptr, 0, 0,
            PtXTf, OUTD, nullptr, 0.f, nullptr);
        castgp_k<<<1088, 256, 0, stream>>>(Gf, PtXTf, Gb, PtXTb);
        // X_{t+1} = Xn + g*(P@PtX - Xn@G); writes `alt`; accumulates ssacc
        gemm_nt_k<128, 128, 1, 0><<<dim3(N_ROWS / 128, DIM / 128, 1), 256, 0, stream>>>(
            xm, DIM, Gb, DIM, 1024,
            Pb, OUTD, PtXTb, OUTD, OUTD,
            (float*)alt, DIM, riv, GAMMA, ssacc);
        rsqrt_k<<<N_ROWS / 256, 256, 0, stream>>>(ssacc, riv);
        ushort* tmp = xm; xm = alt; alt = tmp;   // ping-pong
    }

    // final: out = relu(X@W1 + b1) @ W2 + b2  (unnormalized master, rv=nullptr)
    zgemm_k<<<N_ROWS / 64, 256, 0, stream>>>(xm, W1T, b1, z, nullptr);
    head_k<<<N_ROWS / 256, 256, 0, stream>>>(z, W2, b2, Pb, PTb, out, 0);
}